// Round 6
// baseline (145.422 us; speedup 1.0000x reference)
//
#include <hip/hip_runtime.h>
#include <hip/hip_bf16.h>

typedef unsigned short u16;
typedef unsigned int u32;
using f32x4 = __attribute__((ext_vector_type(4))) float;
using s16x8 = __attribute__((ext_vector_type(8))) short;

#define BATCH 4
#define SEQ   4096
#define CDIM  1024
#define HDIM  64
#define QT_N  256          // 16-row q-tiles per batch

// HW bf16 convert (RNE): gfx950 lowers __bf16 casts to v_cvt_pk_bf16_f32
// class ops (round-5 win vs 3-op software RNE).
__device__ inline u16 f32_to_bf16(float f) {
    __bf16 h = (__bf16)f;
    return __builtin_bit_cast(u16, h);
}
__device__ inline u32 pkbf16(float a, float b) {   // packed bf16x2, RNE
    return (u32)f32_to_bf16(a) | ((u32)f32_to_bf16(b) << 16);
}
__device__ inline f32x4 mfma16(s16x8 a, s16x8 b, f32x4 c) {
    return __builtin_amdgcn_mfma_f32_16x16x32_bf16(a, b, c, 0, 0, 0);
}

// ---- Fragment-interleaved global layouts (lane = quad*16 + l16) ----
// Wtf[nt][kc][lane][8]  = Wcat[n=nt*16+l16][k=kc*32+quad*8+j]   (B-frag, n-major)
// kf [b][kt][hc][lane][8] = K[b][kt*16+l16][hc*32+quad*8+j]     (A-frag for S^T)
// qf [b][qt][hc][lane][8] = Q[b][qt*16+l16][hc*32+quad*8+j]     (B-frag for S^T)
// vf [b][kc][ht][lane][8] = V[b][kc*32+quad*8+j][ht*16+l16]     (A-frag for O^T)

// Kernel 0: W (fp32 [1024][64] x3) -> Wtf bf16 frags. 384 blocks x 64 thr.
__global__ __launch_bounds__(64) void wtrans_kernel(
        const float* __restrict__ Wk, const float* __restrict__ Wq,
        const float* __restrict__ Wv, u16* __restrict__ Wtf) {
    int bx = blockIdx.x;              // (nt, kc)
    int nt = bx >> 5, kc = bx & 31;
    int lane = threadIdx.x;
    int l16 = lane & 15, qd = lane >> 4;
    int n = nt * 16 + l16;
    int a = n >> 6, h = n & 63;
    const float* src = (a == 0) ? Wk : (a == 1) ? Wq : Wv;
    float scale = (a == 1) ? 0.045084220027780106f : 1.0f;  // 1/32 * log2(e)
    u32 p[4];
#pragma unroll
    for (int pp = 0; pp < 4; ++pp) {
        int k = kc * 32 + qd * 8 + pp * 2;
        p[pp] = pkbf16(src[k * HDIM + h] * scale, src[(k + 1) * HDIM + h] * scale);
    }
    uint4 u; u.x = p[0]; u.y = p[1]; u.z = p[2]; u.w = p[3];
    *(uint4*)&Wtf[(size_t)((nt * 32 + kc) * 64 + lane) * 8] = u;
}

// Kernel 1: projection. 512 blocks x 512 thr (8 waves), 32 x-rows per block.
// W-reuse: 24 work-units (12 nt x 2 row-halves), 3 per wave -> every wave's
// 3 units span exactly 2 nt: 2 B-loads feed 3 MFMAs. 66 KB LDS -> 2 blocks/CU
// x 8 waves = 4 waves/SIMD. Wave-parity MFMA pattern in static branches.
__global__ __launch_bounds__(512, 4) void proj_kernel(
        const float* __restrict__ x, const u16* __restrict__ Wtf,
        u16* __restrict__ qf, u16* __restrict__ kf, u16* __restrict__ vf) {
    __shared__ __align__(16) u16 xs[32][1032];   // +8 pad: frag reads 2-way (free)
    int t = threadIdx.x, lane = t & 63, w = t >> 6;
    int quad = lane >> 4, l16 = lane & 15;
    int row0 = blockIdx.x * 32;

    const float* xb = x + (size_t)row0 * CDIM;
#pragma unroll 4
    for (int i = 0; i < 8; ++i) {        // 512 thr x 8 floats = 4 rows/iter
        int flat = i * 4096 + t * 8;
        float4 f0 = *(const float4*)(xb + flat);
        float4 f1 = *(const float4*)(xb + flat + 4);
        uint4 u;
        u.x = pkbf16(f0.x, f0.y); u.y = pkbf16(f0.z, f0.w);
        u.z = pkbf16(f1.x, f1.y); u.w = pkbf16(f1.z, f1.w);
        *(uint4*)&xs[flat >> 10][flat & 1023] = u;
    }
    __syncthreads();

    f32x4 acc[3];
#pragma unroll
    for (int n = 0; n < 3; ++n) acc[n] = (f32x4){0.f, 0.f, 0.f, 0.f};

    // wave w owns units u = 3w..3w+2, unit u = (nt = u>>1, row-half = u&1)
    int nt_lo = (3 * w) >> 1;
    const u16* bp0 = Wtf + ((size_t)(nt_lo * 32) * 64 + lane) * 8;
    const u16* bp1 = bp0 + (size_t)32 * 64 * 8;          // nt_lo + 1

    if ((w & 1) == 0) {   // units: (nt_lo,h0) (nt_lo,h1) (nt_lo+1,h0)
#pragma unroll 4
        for (int kc = 0; kc < 32; ++kc) {
            s16x8 a0 = *(const s16x8*)&xs[l16][kc * 32 + quad * 8];
            s16x8 a1 = *(const s16x8*)&xs[16 + l16][kc * 32 + quad * 8];
            s16x8 b0 = *(const s16x8*)(bp0 + (size_t)kc * 512);
            s16x8 b1 = *(const s16x8*)(bp1 + (size_t)kc * 512);
            acc[0] = mfma16(a0, b0, acc[0]);
            acc[1] = mfma16(a1, b0, acc[1]);
            acc[2] = mfma16(a0, b1, acc[2]);
        }
    } else {              // units: (nt_lo,h1) (nt_lo+1,h0) (nt_lo+1,h1)
#pragma unroll 4
        for (int kc = 0; kc < 32; ++kc) {
            s16x8 a0 = *(const s16x8*)&xs[l16][kc * 32 + quad * 8];
            s16x8 a1 = *(const s16x8*)&xs[16 + l16][kc * 32 + quad * 8];
            s16x8 b0 = *(const s16x8*)(bp0 + (size_t)kc * 512);
            s16x8 b1 = *(const s16x8*)(bp1 + (size_t)kc * 512);
            acc[0] = mfma16(a1, b0, acc[0]);
            acc[1] = mfma16(a0, b1, acc[1]);
            acc[2] = mfma16(a1, b1, acc[2]);
        }
    }

    // epilogue: scatter into fragment-interleaved kf/qf/vf
#pragma unroll
    for (int i = 0; i < 3; ++i) {
        int u = 3 * w + i;
        int nt = u >> 1, rh = u & 1;
        int n0 = nt * 16;
        int rbase = row0 + rh * 16 + quad * 4;   // C-layout: row=quad*4+r, col=l16
        int bb = rbase >> 12, rl = rbase & 4095;
        if (n0 < 128) {                   // k or q
            u16* dst = (n0 < 64) ? kf : qf;
            int h = (n0 & 63) + l16;
            int tt16 = rl >> 4, hc = h >> 5, qd2 = (h >> 3) & 3, j = h & 7;
            size_t base = ((size_t)((bb * 256 + tt16) * 2 + hc) * 64
                           + qd2 * 16 + (rl & 15)) * 8 + j;
#pragma unroll
            for (int r = 0; r < 4; ++r)
                dst[base + (size_t)r * 8] = f32_to_bf16(acc[i][r]);
        } else {                          // v: j = rl&7 + r contiguous -> b64
            int ht = (n0 - 128) >> 4;
            int kc2 = rl >> 5, qdv = (rl >> 3) & 3, j0 = rl & 7;
            u32 lo = pkbf16(acc[i][0], acc[i][1]);
            u32 hi = pkbf16(acc[i][2], acc[i][3]);
            size_t base = ((size_t)((bb * 128 + kc2) * 4 + ht) * 64
                           + qdv * 16 + l16) * 8 + j0;
            uint2 u2; u2.x = lo; u2.y = hi;
            *(uint2*)&vf[base] = u2;
        }
    }
}

// Kernel 2: flash attention, S^T/O^T orientation, 32 q-rows per block,
// 8-WAY key split (512 thr), balanced block->tile mapping.
// THIS ROUND: cross-iteration K-PREFETCH pipeline. Previously next key-
// block's 8 K-frag loads (L2 ~200cyc) issued only after the prior PV
// cluster -> fully exposed latency every iteration. Now K lives in kk[8];
// next block's loads issue right after S^T+pack consume the current ones,
// covered by the exp/bpermute/PV section. Enabler: exp/pack moved inside
// the kt loop (sT transients 32->8 VGPRs pays for kk's +32 under the
// 128-VGPR cap). Same per-element ops and rounding -> bit-identical.
// Plus s_setprio(1) around the PV MFMA cluster (T5: attn-positive regime:
// barrier-free, waves at different phases).
__global__ __launch_bounds__(512, 4) void flash_kernel(
        const u16* __restrict__ qf, const u16* __restrict__ kf,
        const u16* __restrict__ vf, float* __restrict__ out) {
    __shared__ float cb[8][32][68];
    __shared__ float lb[8][32];
    int t = threadIdx.x, w = t >> 6, lane = t & 63;
    int quad = lane >> 4, l16 = lane & 15;
    int bx = blockIdx.x;
    int b = bx & 3;
    int j = (bx & 255) >> 2;
    int qt2 = (bx < 256) ? (127 - j) : j;   // 32-row tile index in [0,128)

    const u16* qp0 = qf + ((size_t)((b * QT_N + qt2 * 2) * 2) * 64 + lane) * 8;
    const u16* qp1 = qp0 + 2 * 64 * 8;     // next 16-tile
    s16x8 bq[2][2];
    bq[0][0] = *(const s16x8*)qp0;
    bq[0][1] = *(const s16x8*)(qp0 + 512);
    bq[1][0] = *(const s16x8*)qp1;
    bq[1][1] = *(const s16x8*)(qp1 + 512);
    s16x8 ones;
#pragma unroll
    for (int jj = 0; jj < 8; ++jj) ones[jj] = (short)0x3F80;

    f32x4 o[2][4], o5[2];
#pragma unroll
    for (int tl = 0; tl < 2; ++tl) {
        o5[tl] = (f32x4){0.f, 0.f, 0.f, 0.f};
#pragma unroll
        for (int i = 0; i < 4; ++i) o[tl][i] = (f32x4){0.f, 0.f, 0.f, 0.f};
    }

    int nb = (qt2 * 32 + 32 + 63) >> 6;  // 64-key causal blocks
    int iters = (nb + 7) >> 3;
    int rowq0 = qt2 * 32 + l16;          // tile0 lane q ; tile1 = +16
    const u16* kfb = kf + (size_t)b * 256 * 2 * 512;
    const u16* vfb = vf + (size_t)b * 128 * 4 * 512;
    int a0 = ((quad & 1) * 32 + l16) * 4;  // bpermute byte addrs
    int a1 = a0 + 64;
    bool lotile = (quad < 2);             // tile-select -> v_cndmask

    s16x8 kk[8];                          // persistent K frags (pipeline)
    auto loadK = [&](int kb) {
#pragma unroll
        for (int kt = 0; kt < 4; ++kt) {
            const u16* kp = kfb + ((size_t)((kb * 4 + kt) * 2) * 64 + lane) * 8;
            kk[2 * kt]     = *(const s16x8*)kp;
            kk[2 * kt + 1] = *(const s16x8*)(kp + 512);
        }
    };

    auto iteration = [&](int kb, int kbn, bool pref, bool domask) {
        // S^T = K Q^T per kt, exp+mask+pack IMMEDIATELY (frees sT + kk[kt])
        u32 P01[2][4], P23[2][4];
#pragma unroll
        for (int kt = 0; kt < 4; ++kt) {
            f32x4 z = (f32x4){0.f, 0.f, 0.f, 0.f};
            f32x4 s0 = mfma16(kk[2 * kt + 1], bq[0][1],
                              mfma16(kk[2 * kt], bq[0][0], z));
            f32x4 s1 = mfma16(kk[2 * kt + 1], bq[1][1],
                              mfma16(kk[2 * kt], bq[1][0], z));
#pragma unroll
            for (int tl = 0; tl < 2; ++tl) {
                f32x4 sv = tl ? s1 : s0;          // static (tl unrolled)
                int rowq = rowq0 + tl * 16;
                float e[4];
#pragma unroll
                for (int r = 0; r < 4; ++r) {
                    float ev = __builtin_amdgcn_exp2f(sv[r]);
                    if (domask) {
                        int key = kb * 64 + kt * 16 + quad * 4 + r;
                        ev = (key > rowq) ? 0.f : ev;
                    }
                    e[r] = ev;
                }
                P01[tl][kt] = pkbf16(e[0], e[1]);
                P23[tl][kt] = pkbf16(e[2], e[3]);
            }
        }
        if (pref) loadK(kbn);   // prefetch next K-block; covered by PV below
        // per 32-key chunk: V A-frags shared by both tiles; P^T via dual
        // full-EXEC bpermute + cndmask select; O^T += V^T P^T; l += 1P^T
#pragma unroll
        for (int c = 0; c < 2; ++c) {
            s16x8 vA[4];
#pragma unroll
            for (int ht = 0; ht < 4; ++ht)
                vA[ht] = *(const s16x8*)&vfb[((size_t)((kb * 2 + c) * 4 + ht) * 64
                                             + lane) * 8];
            int t0 = 2 * c, t1 = 2 * c + 1;
#pragma unroll
            for (int tl = 0; tl < 2; ++tl) {
                u32 x0 = (u32)__builtin_amdgcn_ds_bpermute(a0, (int)P01[tl][t0]);
                u32 y0 = (u32)__builtin_amdgcn_ds_bpermute(a0, (int)P01[tl][t1]);
                u32 x1 = (u32)__builtin_amdgcn_ds_bpermute(a0, (int)P23[tl][t0]);
                u32 y1 = (u32)__builtin_amdgcn_ds_bpermute(a0, (int)P23[tl][t1]);
                u32 x2 = (u32)__builtin_amdgcn_ds_bpermute(a1, (int)P01[tl][t0]);
                u32 y2 = (u32)__builtin_amdgcn_ds_bpermute(a1, (int)P01[tl][t1]);
                u32 x3 = (u32)__builtin_amdgcn_ds_bpermute(a1, (int)P23[tl][t0]);
                u32 y3 = (u32)__builtin_amdgcn_ds_bpermute(a1, (int)P23[tl][t1]);
                uint4 pu;
                pu.x = lotile ? x0 : y0;
                pu.y = lotile ? x1 : y1;
                pu.z = lotile ? x2 : y2;
                pu.w = lotile ? x3 : y3;
                s16x8 pb = __builtin_bit_cast(s16x8, pu);
                __builtin_amdgcn_s_setprio(1);
#pragma unroll
                for (int ht = 0; ht < 4; ++ht)
                    o[tl][ht] = mfma16(vA[ht], pb, o[tl][ht]);
                o5[tl] = mfma16(ones, pb, o5[tl]);
                __builtin_amdgcn_s_setprio(0);
            }
        }
    };

    loadK(w);                             // w <= 7 < 64: always in-bounds
    for (int i = 0; i < iters - 1; ++i) {
        int kb = 8 * i + w;               // always < nb in this range
        int kbn = kb + 8; if (kbn > 63) kbn = 63;   // clamp: valid memory
        iteration(kb, kbn, true, false);
    }
    {
        int kb = 8 * (iters - 1) + w;
        if (kb < nb) iteration(kb, kb, false, true);  // mask harmless for full blocks
    }
    // combine 8 key-split partials (static max: pure addition)
#pragma unroll
    for (int tl = 0; tl < 2; ++tl) {
#pragma unroll
        for (int ht = 0; ht < 4; ++ht)
#pragma unroll
            for (int r = 0; r < 4; ++r)
                cb[w][tl * 16 + l16][ht * 16 + quad * 4 + r] = o[tl][ht][r];
        if (quad == 0) lb[w][tl * 16 + l16] = o5[tl][0];
    }
    __syncthreads();
    int row = t >> 4, c0 = (t & 15) * 4;   // 512 thr cover 32 rows x 64 cols
    float l = 0.f;
    float4 s = (float4){0.f, 0.f, 0.f, 0.f};
#pragma unroll
    for (int w8 = 0; w8 < 8; ++w8) {
        l += lb[w8][row];
        float4 p = *(const float4*)&cb[w8][row][c0];
        s.x += p.x; s.y += p.y; s.z += p.z; s.w += p.w;
    }
    float rcp = 1.0f / l;
    s.x *= rcp; s.y *= rcp; s.z *= rcp; s.w *= rcp;
    *(float4*)&out[((size_t)(b * SEQ) + qt2 * 32 + row) * HDIM + c0] = s;
}

extern "C" void kernel_launch(void* const* d_in, const int* in_sizes, int n_in,
                              void* d_out, int out_size, void* d_ws, size_t ws_size,
                              hipStream_t stream) {
    const float* x  = (const float*)d_in[0];
    const float* Wk = (const float*)d_in[1];
    const float* Wq = (const float*)d_in[2];
    const float* Wv = (const float*)d_in[3];
    u16* wsu = (u16*)d_ws;
    u16* Wtf = wsu;                         // 12*32*64*8      = 196608 u16
    u16* kf  = Wtf + 196608;                // 4*256*2*64*8    = 1048576
    u16* qf  = kf + 1048576;
    u16* vf  = qf + 1048576;                // 4*128*4*64*8    = 1048576
    float* out = (float*)d_out;

    hipLaunchKernelGGL(wtrans_kernel, dim3(384), dim3(64), 0, stream, Wk, Wq, Wv, Wtf);
    hipLaunchKernelGGL(proj_kernel, dim3(512), dim3(512), 0, stream, x, Wtf, qf, kf, vf);
    hipLaunchKernelGGL(flash_kernel, dim3((SEQ / 32) * BATCH), dim3(512), 0, stream,
                       qf, kf, vf, out);
}

// Round 7
// 123.210 us; speedup vs baseline: 1.1803x; 1.1803x over previous
//
#include <hip/hip_runtime.h>
#include <hip/hip_bf16.h>

typedef unsigned short u16;
typedef unsigned int u32;
using f32x4 = __attribute__((ext_vector_type(4))) float;
using s16x8 = __attribute__((ext_vector_type(8))) short;

#define BATCH 4
#define SEQ   4096
#define CDIM  1024
#define HDIM  64
#define QT_N  256          // 16-row q-tiles per batch

// HW bf16 convert (RNE): gfx950 lowers __bf16 casts to v_cvt_pk_bf16_f32
// class ops (round-5 win vs 3-op software RNE).
__device__ inline u16 f32_to_bf16(float f) {
    __bf16 h = (__bf16)f;
    return __builtin_bit_cast(u16, h);
}
__device__ inline u32 pkbf16(float a, float b) {   // packed bf16x2, RNE
    return (u32)f32_to_bf16(a) | ((u32)f32_to_bf16(b) << 16);
}
__device__ inline f32x4 mfma16(s16x8 a, s16x8 b, f32x4 c) {
    return __builtin_amdgcn_mfma_f32_16x16x32_bf16(a, b, c, 0, 0, 0);
}

// ---- Fragment-interleaved global layouts (lane = quad*16 + l16) ----
// Wtf[nt][kc][lane][8]  = Wcat[n=nt*16+l16][k=kc*32+quad*8+j]   (B-frag, n-major)
// kf [b][kt][hc][lane][8] = K[b][kt*16+l16][hc*32+quad*8+j]     (A-frag for S^T)
// qf [b][qt][hc][lane][8] = Q[b][qt*16+l16][hc*32+quad*8+j]     (B-frag for S^T)
// vf [b][kc][ht][lane][8] = V[b][kc*32+quad*8+j][ht*16+l16]     (A-frag for O^T)

// Kernel 0: W (fp32 [1024][64] x3) -> Wtf bf16 frags. 384 blocks x 64 thr.
__global__ __launch_bounds__(64) void wtrans_kernel(
        const float* __restrict__ Wk, const float* __restrict__ Wq,
        const float* __restrict__ Wv, u16* __restrict__ Wtf) {
    int bx = blockIdx.x;              // (nt, kc)
    int nt = bx >> 5, kc = bx & 31;
    int lane = threadIdx.x;
    int l16 = lane & 15, qd = lane >> 4;
    int n = nt * 16 + l16;
    int a = n >> 6, h = n & 63;
    const float* src = (a == 0) ? Wk : (a == 1) ? Wq : Wv;
    float scale = (a == 1) ? 0.045084220027780106f : 1.0f;  // 1/32 * log2(e)
    u32 p[4];
#pragma unroll
    for (int pp = 0; pp < 4; ++pp) {
        int k = kc * 32 + qd * 8 + pp * 2;
        p[pp] = pkbf16(src[k * HDIM + h] * scale, src[(k + 1) * HDIM + h] * scale);
    }
    uint4 u; u.x = p[0]; u.y = p[1]; u.z = p[2]; u.w = p[3];
    *(uint4*)&Wtf[(size_t)((nt * 32 + kc) * 64 + lane) * 8] = u;
}

// Kernel 1: projection. 512 blocks x 512 thr (8 waves), 32 x-rows per block.
// W-reuse: 24 work-units (12 nt x 2 row-halves), 3 per wave -> every wave's
// 3 units span exactly 2 nt: 2 B-loads feed 3 MFMAs. 66 KB LDS -> 2 blocks/CU
// x 8 waves = 4 waves/SIMD. Wave-parity MFMA pattern in static branches.
__global__ __launch_bounds__(512, 4) void proj_kernel(
        const float* __restrict__ x, const u16* __restrict__ Wtf,
        u16* __restrict__ qf, u16* __restrict__ kf, u16* __restrict__ vf) {
    __shared__ __align__(16) u16 xs[32][1032];   // +8 pad: frag reads 2-way (free)
    int t = threadIdx.x, lane = t & 63, w = t >> 6;
    int quad = lane >> 4, l16 = lane & 15;
    int row0 = blockIdx.x * 32;

    const float* xb = x + (size_t)row0 * CDIM;
#pragma unroll 4
    for (int i = 0; i < 8; ++i) {        // 512 thr x 8 floats = 4 rows/iter
        int flat = i * 4096 + t * 8;
        float4 f0 = *(const float4*)(xb + flat);
        float4 f1 = *(const float4*)(xb + flat + 4);
        uint4 u;
        u.x = pkbf16(f0.x, f0.y); u.y = pkbf16(f0.z, f0.w);
        u.z = pkbf16(f1.x, f1.y); u.w = pkbf16(f1.z, f1.w);
        *(uint4*)&xs[flat >> 10][flat & 1023] = u;
    }
    __syncthreads();

    f32x4 acc[3];
#pragma unroll
    for (int n = 0; n < 3; ++n) acc[n] = (f32x4){0.f, 0.f, 0.f, 0.f};

    // wave w owns units u = 3w..3w+2, unit u = (nt = u>>1, row-half = u&1)
    int nt_lo = (3 * w) >> 1;
    const u16* bp0 = Wtf + ((size_t)(nt_lo * 32) * 64 + lane) * 8;
    const u16* bp1 = bp0 + (size_t)32 * 64 * 8;          // nt_lo + 1

    if ((w & 1) == 0) {   // units: (nt_lo,h0) (nt_lo,h1) (nt_lo+1,h0)
#pragma unroll 4
        for (int kc = 0; kc < 32; ++kc) {
            s16x8 a0 = *(const s16x8*)&xs[l16][kc * 32 + quad * 8];
            s16x8 a1 = *(const s16x8*)&xs[16 + l16][kc * 32 + quad * 8];
            s16x8 b0 = *(const s16x8*)(bp0 + (size_t)kc * 512);
            s16x8 b1 = *(const s16x8*)(bp1 + (size_t)kc * 512);
            acc[0] = mfma16(a0, b0, acc[0]);
            acc[1] = mfma16(a1, b0, acc[1]);
            acc[2] = mfma16(a0, b1, acc[2]);
        }
    } else {              // units: (nt_lo,h1) (nt_lo+1,h0) (nt_lo+1,h1)
#pragma unroll 4
        for (int kc = 0; kc < 32; ++kc) {
            s16x8 a0 = *(const s16x8*)&xs[l16][kc * 32 + quad * 8];
            s16x8 a1 = *(const s16x8*)&xs[16 + l16][kc * 32 + quad * 8];
            s16x8 b0 = *(const s16x8*)(bp0 + (size_t)kc * 512);
            s16x8 b1 = *(const s16x8*)(bp1 + (size_t)kc * 512);
            acc[0] = mfma16(a1, b0, acc[0]);
            acc[1] = mfma16(a0, b1, acc[1]);
            acc[2] = mfma16(a1, b1, acc[2]);
        }
    }

    // epilogue: scatter into fragment-interleaved kf/qf/vf
#pragma unroll
    for (int i = 0; i < 3; ++i) {
        int u = 3 * w + i;
        int nt = u >> 1, rh = u & 1;
        int n0 = nt * 16;
        int rbase = row0 + rh * 16 + quad * 4;   // C-layout: row=quad*4+r, col=l16
        int bb = rbase >> 12, rl = rbase & 4095;
        if (n0 < 128) {                   // k or q
            u16* dst = (n0 < 64) ? kf : qf;
            int h = (n0 & 63) + l16;
            int tt16 = rl >> 4, hc = h >> 5, qd2 = (h >> 3) & 3, j = h & 7;
            size_t base = ((size_t)((bb * 256 + tt16) * 2 + hc) * 64
                           + qd2 * 16 + (rl & 15)) * 8 + j;
#pragma unroll
            for (int r = 0; r < 4; ++r)
                dst[base + (size_t)r * 8] = f32_to_bf16(acc[i][r]);
        } else {                          // v: j = rl&7 + r contiguous -> b64
            int ht = (n0 - 128) >> 4;
            int kc2 = rl >> 5, qdv = (rl >> 3) & 3, j0 = rl & 7;
            u32 lo = pkbf16(acc[i][0], acc[i][1]);
            u32 hi = pkbf16(acc[i][2], acc[i][3]);
            size_t base = ((size_t)((bb * 128 + kc2) * 4 + ht) * 64
                           + qdv * 16 + l16) * 8 + j0;
            uint2 u2; u2.x = lo; u2.y = hi;
            *(uint2*)&vf[base] = u2;
        }
    }
}

// Kernel 2: flash attention, S^T/O^T orientation, 32 q-rows per block,
// 8-WAY key split (512 thr), balanced block->tile mapping (pairs sum to 65
// key-blocks). ROUND 7: REVERT round-6's persistent-K prefetch -- kk[8]
// (+64 VGPR) blew the 128-VGPR cap of __launch_bounds__(512,4) and spilled
// to scratch (flash WRITE_SIZE 46 MB vs 4 MB legit output -> +20us). Back
// to the round-5 structure (known-good 125.4us), single added variable:
// s_setprio(1/0) around both MFMA clusters (T5: +4-7% attn in this regime;
// 0 VGPR cost, cannot spill).
__global__ __launch_bounds__(512, 4) void flash_kernel(
        const u16* __restrict__ qf, const u16* __restrict__ kf,
        const u16* __restrict__ vf, float* __restrict__ out) {
    __shared__ float cb[8][32][68];
    __shared__ float lb[8][32];
    int t = threadIdx.x, w = t >> 6, lane = t & 63;
    int quad = lane >> 4, l16 = lane & 15;
    int bx = blockIdx.x;
    int b = bx & 3;
    int j = (bx & 255) >> 2;
    int qt2 = (bx < 256) ? (127 - j) : j;   // 32-row tile index in [0,128)

    const u16* qp0 = qf + ((size_t)((b * QT_N + qt2 * 2) * 2) * 64 + lane) * 8;
    const u16* qp1 = qp0 + 2 * 64 * 8;     // next 16-tile
    s16x8 bq[2][2];
    bq[0][0] = *(const s16x8*)qp0;
    bq[0][1] = *(const s16x8*)(qp0 + 512);
    bq[1][0] = *(const s16x8*)qp1;
    bq[1][1] = *(const s16x8*)(qp1 + 512);
    s16x8 ones;
#pragma unroll
    for (int jj = 0; jj < 8; ++jj) ones[jj] = (short)0x3F80;

    f32x4 o[2][4], o5[2];
#pragma unroll
    for (int tl = 0; tl < 2; ++tl) {
        o5[tl] = (f32x4){0.f, 0.f, 0.f, 0.f};
#pragma unroll
        for (int i = 0; i < 4; ++i) o[tl][i] = (f32x4){0.f, 0.f, 0.f, 0.f};
    }

    int nb = (qt2 * 32 + 32 + 63) >> 6;  // 64-key causal blocks
    int iters = (nb + 7) >> 3;
    int rowq0 = qt2 * 32 + l16;          // tile0 lane q ; tile1 = +16
    const u16* kfb = kf + (size_t)b * 256 * 2 * 512;
    const u16* vfb = vf + (size_t)b * 128 * 4 * 512;
    int a0 = ((quad & 1) * 32 + l16) * 4;  // bpermute byte addrs
    int a1 = a0 + 64;
    bool lotile = (quad < 2);             // tile-select -> v_cndmask

    auto iteration = [&](int kb, bool domask) {
        // S^T = K Q^T : K A-frags loaded once, feed BOTH q-tiles
        f32x4 sT[2][4];
        __builtin_amdgcn_s_setprio(1);
#pragma unroll
        for (int kt = 0; kt < 4; ++kt) {
            const u16* kp = kfb + ((size_t)((kb * 4 + kt) * 2) * 64 + lane) * 8;
            s16x8 k0 = *(const s16x8*)kp;
            s16x8 k1 = *(const s16x8*)(kp + 512);
            f32x4 z = (f32x4){0.f, 0.f, 0.f, 0.f};
            sT[0][kt] = mfma16(k1, bq[0][1], mfma16(k0, bq[0][0], z));
            sT[1][kt] = mfma16(k1, bq[1][1], mfma16(k0, bq[1][0], z));
        }
        __builtin_amdgcn_s_setprio(0);
        // exp2 (scale+log2e folded into Wq), mask only diagonal block, pack
        u32 P01[2][4], P23[2][4];
#pragma unroll
        for (int tl = 0; tl < 2; ++tl) {
            int rowq = rowq0 + tl * 16;
#pragma unroll
            for (int kt = 0; kt < 4; ++kt) {
                float e[4];
#pragma unroll
                for (int r = 0; r < 4; ++r) {
                    float ev = __builtin_amdgcn_exp2f(sT[tl][kt][r]);
                    if (domask) {
                        int key = kb * 64 + kt * 16 + quad * 4 + r;
                        ev = (key > rowq) ? 0.f : ev;
                    }
                    e[r] = ev;
                }
                P01[tl][kt] = pkbf16(e[0], e[1]);
                P23[tl][kt] = pkbf16(e[2], e[3]);
            }
        }
        // per 32-key chunk: V A-frags shared by both tiles; P^T via dual
        // full-EXEC bpermute + cndmask select; O^T += V^T P^T; l += 1P^T
#pragma unroll
        for (int c = 0; c < 2; ++c) {
            s16x8 vA[4];
#pragma unroll
            for (int ht = 0; ht < 4; ++ht)
                vA[ht] = *(const s16x8*)&vfb[((size_t)((kb * 2 + c) * 4 + ht) * 64
                                             + lane) * 8];
            int t0 = 2 * c, t1 = 2 * c + 1;
#pragma unroll
            for (int tl = 0; tl < 2; ++tl) {
                u32 x0 = (u32)__builtin_amdgcn_ds_bpermute(a0, (int)P01[tl][t0]);
                u32 y0 = (u32)__builtin_amdgcn_ds_bpermute(a0, (int)P01[tl][t1]);
                u32 x1 = (u32)__builtin_amdgcn_ds_bpermute(a0, (int)P23[tl][t0]);
                u32 y1 = (u32)__builtin_amdgcn_ds_bpermute(a0, (int)P23[tl][t1]);
                u32 x2 = (u32)__builtin_amdgcn_ds_bpermute(a1, (int)P01[tl][t0]);
                u32 y2 = (u32)__builtin_amdgcn_ds_bpermute(a1, (int)P01[tl][t1]);
                u32 x3 = (u32)__builtin_amdgcn_ds_bpermute(a1, (int)P23[tl][t0]);
                u32 y3 = (u32)__builtin_amdgcn_ds_bpermute(a1, (int)P23[tl][t1]);
                uint4 pu;
                pu.x = lotile ? x0 : y0;
                pu.y = lotile ? x1 : y1;
                pu.z = lotile ? x2 : y2;
                pu.w = lotile ? x3 : y3;
                s16x8 pb = __builtin_bit_cast(s16x8, pu);
                __builtin_amdgcn_s_setprio(1);
#pragma unroll
                for (int ht = 0; ht < 4; ++ht)
                    o[tl][ht] = mfma16(vA[ht], pb, o[tl][ht]);
                o5[tl] = mfma16(ones, pb, o5[tl]);
                __builtin_amdgcn_s_setprio(0);
            }
        }
    };

    for (int i = 0; i < iters - 1; ++i) iteration(8 * i + w, false);
    {
        int kb = 8 * (iters - 1) + w;
        if (kb < nb) iteration(kb, true);   // mask harmless for full blocks
    }
    // combine 8 key-split partials (static max: pure addition)
#pragma unroll
    for (int tl = 0; tl < 2; ++tl) {
#pragma unroll
        for (int ht = 0; ht < 4; ++ht)
#pragma unroll
            for (int r = 0; r < 4; ++r)
                cb[w][tl * 16 + l16][ht * 16 + quad * 4 + r] = o[tl][ht][r];
        if (quad == 0) lb[w][tl * 16 + l16] = o5[tl][0];
    }
    __syncthreads();
    int row = t >> 4, c0 = (t & 15) * 4;   // 512 thr cover 32 rows x 64 cols
    float l = 0.f;
    float4 s = (float4){0.f, 0.f, 0.f, 0.f};
#pragma unroll
    for (int w8 = 0; w8 < 8; ++w8) {
        l += lb[w8][row];
        float4 p = *(const float4*)&cb[w8][row][c0];
        s.x += p.x; s.y += p.y; s.z += p.z; s.w += p.w;
    }
    float rcp = 1.0f / l;
    s.x *= rcp; s.y *= rcp; s.z *= rcp; s.w *= rcp;
    *(float4*)&out[((size_t)(b * SEQ) + qt2 * 32 + row) * HDIM + c0] = s;
}

extern "C" void kernel_launch(void* const* d_in, const int* in_sizes, int n_in,
                              void* d_out, int out_size, void* d_ws, size_t ws_size,
                              hipStream_t stream) {
    const float* x  = (const float*)d_in[0];
    const float* Wk = (const float*)d_in[1];
    const float* Wq = (const float*)d_in[2];
    const float* Wv = (const float*)d_in[3];
    u16* wsu = (u16*)d_ws;
    u16* Wtf = wsu;                         // 12*32*64*8      = 196608 u16
    u16* kf  = Wtf + 196608;                // 4*256*2*64*8    = 1048576
    u16* qf  = kf + 1048576;
    u16* vf  = qf + 1048576;                // 4*128*4*64*8    = 1048576
    float* out = (float*)d_out;

    hipLaunchKernelGGL(wtrans_kernel, dim3(384), dim3(64), 0, stream, Wk, Wq, Wv, Wtf);
    hipLaunchKernelGGL(proj_kernel, dim3(512), dim3(512), 0, stream, x, Wtf, qf, kf, vf);
    hipLaunchKernelGGL(flash_kernel, dim3((SEQ / 32) * BATCH), dim3(512), 0, stream,
                       qf, kf, vf, out);
}

// Round 8
// 121.876 us; speedup vs baseline: 1.1932x; 1.0109x over previous
//
#include <hip/hip_runtime.h>
#include <hip/hip_bf16.h>

typedef unsigned short u16;
typedef unsigned int u32;
using f32x4 = __attribute__((ext_vector_type(4))) float;
using s16x8 = __attribute__((ext_vector_type(8))) short;

#define BATCH 4
#define SEQ   4096
#define CDIM  1024
#define HDIM  64
#define QT_N  256          // 16-row q-tiles per batch

// HW bf16 convert (RNE): gfx950 lowers __bf16 casts to v_cvt_pk_bf16_f32
// class ops (round-5 win vs 3-op software RNE).
__device__ inline u16 f32_to_bf16(float f) {
    __bf16 h = (__bf16)f;
    return __builtin_bit_cast(u16, h);
}
__device__ inline u32 pkbf16(float a, float b) {   // packed bf16x2, RNE
    return (u32)f32_to_bf16(a) | ((u32)f32_to_bf16(b) << 16);
}
__device__ inline f32x4 mfma16(s16x8 a, s16x8 b, f32x4 c) {
    return __builtin_amdgcn_mfma_f32_16x16x32_bf16(a, b, c, 0, 0, 0);
}

// ---- Fragment-interleaved global layouts (lane = quad*16 + l16) ----
// Wtf[nt][kc][lane][8]  = Wcat[n=nt*16+l16][k=kc*32+quad*8+j]   (B-frag, n-major)
// kf [b][kt][hc][lane][8] = K[b][kt*16+l16][hc*32+quad*8+j]     (A-frag for S^T)
// qf [b][qt][hc][lane][8] = Q[b][qt*16+l16][hc*32+quad*8+j]     (B-frag for S^T)
// vf [b][kc][ht][lane][8] = V[b][kc*32+quad*8+j][ht*16+l16]     (A-frag for O^T)

// ROUND 8: LAUNCH-BOUNDS FIX. Round-6's one visible flash row showed
// VGPR_Count=64: on this toolchain __launch_bounds__'s 2nd arg acts like
// CUDA minBlocksPerCU -> (512,4) = 2048 thr/CU = 131072/2048 = 64-VGPR cap.
// flash's live set (~100+ regs) and proj's staging transients CANNOT fit
// in 64 -> both kernels have been scratch-spilling in every round (round-6
// just made it catastrophic: 46 MB spill writes). (512,2) -> 1024 thr/CU
// -> 128-VGPR cap. Occupancy unchanged: LDS (66-70 KB) already limits to
// exactly 2 blocks/CU = 4 waves/SIMD. No other changes vs round 7.

// Kernel 0: W (fp32 [1024][64] x3) -> Wtf bf16 frags. 384 blocks x 64 thr.
__global__ __launch_bounds__(64) void wtrans_kernel(
        const float* __restrict__ Wk, const float* __restrict__ Wq,
        const float* __restrict__ Wv, u16* __restrict__ Wtf) {
    int bx = blockIdx.x;              // (nt, kc)
    int nt = bx >> 5, kc = bx & 31;
    int lane = threadIdx.x;
    int l16 = lane & 15, qd = lane >> 4;
    int n = nt * 16 + l16;
    int a = n >> 6, h = n & 63;
    const float* src = (a == 0) ? Wk : (a == 1) ? Wq : Wv;
    float scale = (a == 1) ? 0.045084220027780106f : 1.0f;  // 1/32 * log2(e)
    u32 p[4];
#pragma unroll
    for (int pp = 0; pp < 4; ++pp) {
        int k = kc * 32 + qd * 8 + pp * 2;
        p[pp] = pkbf16(src[k * HDIM + h] * scale, src[(k + 1) * HDIM + h] * scale);
    }
    uint4 u; u.x = p[0]; u.y = p[1]; u.z = p[2]; u.w = p[3];
    *(uint4*)&Wtf[(size_t)((nt * 32 + kc) * 64 + lane) * 8] = u;
}

// Kernel 1: projection. 512 blocks x 512 thr (8 waves), 32 x-rows per block.
// W-reuse: 24 work-units (12 nt x 2 row-halves), 3 per wave -> every wave's
// 3 units span exactly 2 nt: 2 B-loads feed 3 MFMAs. 66 KB LDS -> 2 blocks/CU
// x 8 waves = 4 waves/SIMD. Wave-parity MFMA pattern in static branches.
__global__ __launch_bounds__(512, 2) void proj_kernel(
        const float* __restrict__ x, const u16* __restrict__ Wtf,
        u16* __restrict__ qf, u16* __restrict__ kf, u16* __restrict__ vf) {
    __shared__ __align__(16) u16 xs[32][1032];   // +8 pad: frag reads 2-way (free)
    int t = threadIdx.x, lane = t & 63, w = t >> 6;
    int quad = lane >> 4, l16 = lane & 15;
    int row0 = blockIdx.x * 32;

    const float* xb = x + (size_t)row0 * CDIM;
#pragma unroll 4
    for (int i = 0; i < 8; ++i) {        // 512 thr x 8 floats = 4 rows/iter
        int flat = i * 4096 + t * 8;
        float4 f0 = *(const float4*)(xb + flat);
        float4 f1 = *(const float4*)(xb + flat + 4);
        uint4 u;
        u.x = pkbf16(f0.x, f0.y); u.y = pkbf16(f0.z, f0.w);
        u.z = pkbf16(f1.x, f1.y); u.w = pkbf16(f1.z, f1.w);
        *(uint4*)&xs[flat >> 10][flat & 1023] = u;
    }
    __syncthreads();

    f32x4 acc[3];
#pragma unroll
    for (int n = 0; n < 3; ++n) acc[n] = (f32x4){0.f, 0.f, 0.f, 0.f};

    // wave w owns units u = 3w..3w+2, unit u = (nt = u>>1, row-half = u&1)
    int nt_lo = (3 * w) >> 1;
    const u16* bp0 = Wtf + ((size_t)(nt_lo * 32) * 64 + lane) * 8;
    const u16* bp1 = bp0 + (size_t)32 * 64 * 8;          // nt_lo + 1

    if ((w & 1) == 0) {   // units: (nt_lo,h0) (nt_lo,h1) (nt_lo+1,h0)
#pragma unroll 4
        for (int kc = 0; kc < 32; ++kc) {
            s16x8 a0 = *(const s16x8*)&xs[l16][kc * 32 + quad * 8];
            s16x8 a1 = *(const s16x8*)&xs[16 + l16][kc * 32 + quad * 8];
            s16x8 b0 = *(const s16x8*)(bp0 + (size_t)kc * 512);
            s16x8 b1 = *(const s16x8*)(bp1 + (size_t)kc * 512);
            acc[0] = mfma16(a0, b0, acc[0]);
            acc[1] = mfma16(a1, b0, acc[1]);
            acc[2] = mfma16(a0, b1, acc[2]);
        }
    } else {              // units: (nt_lo,h1) (nt_lo+1,h0) (nt_lo+1,h1)
#pragma unroll 4
        for (int kc = 0; kc < 32; ++kc) {
            s16x8 a0 = *(const s16x8*)&xs[l16][kc * 32 + quad * 8];
            s16x8 a1 = *(const s16x8*)&xs[16 + l16][kc * 32 + quad * 8];
            s16x8 b0 = *(const s16x8*)(bp0 + (size_t)kc * 512);
            s16x8 b1 = *(const s16x8*)(bp1 + (size_t)kc * 512);
            acc[0] = mfma16(a1, b0, acc[0]);
            acc[1] = mfma16(a0, b1, acc[1]);
            acc[2] = mfma16(a1, b1, acc[2]);
        }
    }

    // epilogue: scatter into fragment-interleaved kf/qf/vf
#pragma unroll
    for (int i = 0; i < 3; ++i) {
        int u = 3 * w + i;
        int nt = u >> 1, rh = u & 1;
        int n0 = nt * 16;
        int rbase = row0 + rh * 16 + quad * 4;   // C-layout: row=quad*4+r, col=l16
        int bb = rbase >> 12, rl = rbase & 4095;
        if (n0 < 128) {                   // k or q
            u16* dst = (n0 < 64) ? kf : qf;
            int h = (n0 & 63) + l16;
            int tt16 = rl >> 4, hc = h >> 5, qd2 = (h >> 3) & 3, j = h & 7;
            size_t base = ((size_t)((bb * 256 + tt16) * 2 + hc) * 64
                           + qd2 * 16 + (rl & 15)) * 8 + j;
#pragma unroll
            for (int r = 0; r < 4; ++r)
                dst[base + (size_t)r * 8] = f32_to_bf16(acc[i][r]);
        } else {                          // v: j = rl&7 + r contiguous -> b64
            int ht = (n0 - 128) >> 4;
            int kc2 = rl >> 5, qdv = (rl >> 3) & 3, j0 = rl & 7;
            u32 lo = pkbf16(acc[i][0], acc[i][1]);
            u32 hi = pkbf16(acc[i][2], acc[i][3]);
            size_t base = ((size_t)((bb * 128 + kc2) * 4 + ht) * 64
                           + qdv * 16 + l16) * 8 + j0;
            uint2 u2; u2.x = lo; u2.y = hi;
            *(uint2*)&vf[base] = u2;
        }
    }
}

// Kernel 2: flash attention, S^T/O^T orientation, 32 q-rows per block,
// 8-WAY key split (512 thr), balanced block->tile mapping (pairs sum to 65
// key-blocks). Round-7 structure (known-good) + setprio; only the VGPR cap
// changed this round (see ROUND 8 note above).
__global__ __launch_bounds__(512, 2) void flash_kernel(
        const u16* __restrict__ qf, const u16* __restrict__ kf,
        const u16* __restrict__ vf, float* __restrict__ out) {
    __shared__ float cb[8][32][68];
    __shared__ float lb[8][32];
    int t = threadIdx.x, w = t >> 6, lane = t & 63;
    int quad = lane >> 4, l16 = lane & 15;
    int bx = blockIdx.x;
    int b = bx & 3;
    int j = (bx & 255) >> 2;
    int qt2 = (bx < 256) ? (127 - j) : j;   // 32-row tile index in [0,128)

    const u16* qp0 = qf + ((size_t)((b * QT_N + qt2 * 2) * 2) * 64 + lane) * 8;
    const u16* qp1 = qp0 + 2 * 64 * 8;     // next 16-tile
    s16x8 bq[2][2];
    bq[0][0] = *(const s16x8*)qp0;
    bq[0][1] = *(const s16x8*)(qp0 + 512);
    bq[1][0] = *(const s16x8*)qp1;
    bq[1][1] = *(const s16x8*)(qp1 + 512);
    s16x8 ones;
#pragma unroll
    for (int jj = 0; jj < 8; ++jj) ones[jj] = (short)0x3F80;

    f32x4 o[2][4], o5[2];
#pragma unroll
    for (int tl = 0; tl < 2; ++tl) {
        o5[tl] = (f32x4){0.f, 0.f, 0.f, 0.f};
#pragma unroll
        for (int i = 0; i < 4; ++i) o[tl][i] = (f32x4){0.f, 0.f, 0.f, 0.f};
    }

    int nb = (qt2 * 32 + 32 + 63) >> 6;  // 64-key causal blocks
    int iters = (nb + 7) >> 3;
    int rowq0 = qt2 * 32 + l16;          // tile0 lane q ; tile1 = +16
    const u16* kfb = kf + (size_t)b * 256 * 2 * 512;
    const u16* vfb = vf + (size_t)b * 128 * 4 * 512;
    int a0 = ((quad & 1) * 32 + l16) * 4;  // bpermute byte addrs
    int a1 = a0 + 64;
    bool lotile = (quad < 2);             // tile-select -> v_cndmask

    auto iteration = [&](int kb, bool domask) {
        // S^T = K Q^T : K A-frags loaded once, feed BOTH q-tiles
        f32x4 sT[2][4];
        __builtin_amdgcn_s_setprio(1);
#pragma unroll
        for (int kt = 0; kt < 4; ++kt) {
            const u16* kp = kfb + ((size_t)((kb * 4 + kt) * 2) * 64 + lane) * 8;
            s16x8 k0 = *(const s16x8*)kp;
            s16x8 k1 = *(const s16x8*)(kp + 512);
            f32x4 z = (f32x4){0.f, 0.f, 0.f, 0.f};
            sT[0][kt] = mfma16(k1, bq[0][1], mfma16(k0, bq[0][0], z));
            sT[1][kt] = mfma16(k1, bq[1][1], mfma16(k0, bq[1][0], z));
        }
        __builtin_amdgcn_s_setprio(0);
        // exp2 (scale+log2e folded into Wq), mask only diagonal block, pack
        u32 P01[2][4], P23[2][4];
#pragma unroll
        for (int tl = 0; tl < 2; ++tl) {
            int rowq = rowq0 + tl * 16;
#pragma unroll
            for (int kt = 0; kt < 4; ++kt) {
                float e[4];
#pragma unroll
                for (int r = 0; r < 4; ++r) {
                    float ev = __builtin_amdgcn_exp2f(sT[tl][kt][r]);
                    if (domask) {
                        int key = kb * 64 + kt * 16 + quad * 4 + r;
                        ev = (key > rowq) ? 0.f : ev;
                    }
                    e[r] = ev;
                }
                P01[tl][kt] = pkbf16(e[0], e[1]);
                P23[tl][kt] = pkbf16(e[2], e[3]);
            }
        }
        // per 32-key chunk: V A-frags shared by both tiles; P^T via dual
        // full-EXEC bpermute + cndmask select; O^T += V^T P^T; l += 1P^T
#pragma unroll
        for (int c = 0; c < 2; ++c) {
            s16x8 vA[4];
#pragma unroll
            for (int ht = 0; ht < 4; ++ht)
                vA[ht] = *(const s16x8*)&vfb[((size_t)((kb * 2 + c) * 4 + ht) * 64
                                             + lane) * 8];
            int t0 = 2 * c, t1 = 2 * c + 1;
#pragma unroll
            for (int tl = 0; tl < 2; ++tl) {
                u32 x0 = (u32)__builtin_amdgcn_ds_bpermute(a0, (int)P01[tl][t0]);
                u32 y0 = (u32)__builtin_amdgcn_ds_bpermute(a0, (int)P01[tl][t1]);
                u32 x1 = (u32)__builtin_amdgcn_ds_bpermute(a0, (int)P23[tl][t0]);
                u32 y1 = (u32)__builtin_amdgcn_ds_bpermute(a0, (int)P23[tl][t1]);
                u32 x2 = (u32)__builtin_amdgcn_ds_bpermute(a1, (int)P01[tl][t0]);
                u32 y2 = (u32)__builtin_amdgcn_ds_bpermute(a1, (int)P01[tl][t1]);
                u32 x3 = (u32)__builtin_amdgcn_ds_bpermute(a1, (int)P23[tl][t0]);
                u32 y3 = (u32)__builtin_amdgcn_ds_bpermute(a1, (int)P23[tl][t1]);
                uint4 pu;
                pu.x = lotile ? x0 : y0;
                pu.y = lotile ? x1 : y1;
                pu.z = lotile ? x2 : y2;
                pu.w = lotile ? x3 : y3;
                s16x8 pb = __builtin_bit_cast(s16x8, pu);
                __builtin_amdgcn_s_setprio(1);
#pragma unroll
                for (int ht = 0; ht < 4; ++ht)
                    o[tl][ht] = mfma16(vA[ht], pb, o[tl][ht]);
                o5[tl] = mfma16(ones, pb, o5[tl]);
                __builtin_amdgcn_s_setprio(0);
            }
        }
    };

    for (int i = 0; i < iters - 1; ++i) iteration(8 * i + w, false);
    {
        int kb = 8 * (iters - 1) + w;
        if (kb < nb) iteration(kb, true);   // mask harmless for full blocks
    }
    // combine 8 key-split partials (static max: pure addition)
#pragma unroll
    for (int tl = 0; tl < 2; ++tl) {
#pragma unroll
        for (int ht = 0; ht < 4; ++ht)
#pragma unroll
            for (int r = 0; r < 4; ++r)
                cb[w][tl * 16 + l16][ht * 16 + quad * 4 + r] = o[tl][ht][r];
        if (quad == 0) lb[w][tl * 16 + l16] = o5[tl][0];
    }
    __syncthreads();
    int row = t >> 4, c0 = (t & 15) * 4;   // 512 thr cover 32 rows x 64 cols
    float l = 0.f;
    float4 s = (float4){0.f, 0.f, 0.f, 0.f};
#pragma unroll
    for (int w8 = 0; w8 < 8; ++w8) {
        l += lb[w8][row];
        float4 p = *(const float4*)&cb[w8][row][c0];
        s.x += p.x; s.y += p.y; s.z += p.z; s.w += p.w;
    }
    float rcp = 1.0f / l;
    s.x *= rcp; s.y *= rcp; s.z *= rcp; s.w *= rcp;
    *(float4*)&out[((size_t)(b * SEQ) + qt2 * 32 + row) * HDIM + c0] = s;
}

extern "C" void kernel_launch(void* const* d_in, const int* in_sizes, int n_in,
                              void* d_out, int out_size, void* d_ws, size_t ws_size,
                              hipStream_t stream) {
    const float* x  = (const float*)d_in[0];
    const float* Wk = (const float*)d_in[1];
    const float* Wq = (const float*)d_in[2];
    const float* Wv = (const float*)d_in[3];
    u16* wsu = (u16*)d_ws;
    u16* Wtf = wsu;                         // 12*32*64*8      = 196608 u16
    u16* kf  = Wtf + 196608;                // 4*256*2*64*8    = 1048576
    u16* qf  = kf + 1048576;
    u16* vf  = qf + 1048576;                // 4*128*4*64*8    = 1048576
    float* out = (float*)d_out;

    hipLaunchKernelGGL(wtrans_kernel, dim3(384), dim3(64), 0, stream, Wk, Wq, Wv, Wtf);
    hipLaunchKernelGGL(proj_kernel, dim3(512), dim3(512), 0, stream, x, Wtf, qf, kf, vf);
    hipLaunchKernelGGL(flash_kernel, dim3((SEQ / 32) * BATCH), dim3(512), 0, stream,
                       qf, kf, vf, out);
}